// Round 9
// baseline (169.445 us; speedup 1.0000x reference)
//
#include <hip/hip_runtime.h>

#define IN_F    4096
#define OUT_F   4096
#define K_DIM   4096
#define NNZ_C   838860
#define BATCH   512
#define BK      32
#define BM      128
#define BN      128
#define NBLK    1024                     // = 4 blocks/CU x 256 CUs, exact
#define SCAT_BLKS 820                    // 820*256*4 >= NNZ_C entries
#define CVT_BLKS  (NBLK - SCAT_BLKS)
#define N_CVT   (BATCH * K_DIM / 8)      // bf16x8 items
#define N_RED   (BATCH * OUT_F / 4)      // float4 items

typedef short bf16x8 __attribute__((ext_vector_type(8)));
typedef float f32x4  __attribute__((ext_vector_type(4)));

__device__ __forceinline__ unsigned short f2bf(float f) {  // RNE fp32->bf16
    unsigned u = __float_as_uint(f);
    u += 0x7fffu + ((u >> 16) & 1u);
    return (unsigned short)(u >> 16);
}
__device__ __forceinline__ void gload_lds16(const void* g, void* l) {
    __builtin_amdgcn_global_load_lds(
        (const __attribute__((address_space(1))) unsigned int*)g,
        (__attribute__((address_space(3))) unsigned int*)l, 16, 0, 0);
}
__device__ __forceinline__ void pk_add(unsigned short* W, int r, int c, float v) {
    unsigned idx = (unsigned)r * K_DIM + (unsigned)c;
    unsigned short h = f2bf(v);
    unsigned data = (idx & 1u) ? ((unsigned)h << 16) : (unsigned)h;
    unsigned long long addr = (unsigned long long)(W + (idx & ~1u));
    asm volatile("global_atomic_pk_add_bf16 %0, %1, off"
                 :: "v"(addr), "v"(data) : "memory");
}

// ---------------------------------------------------------------------------
// Device-scope grid barrier. All 1024 blocks are co-resident (enforced by the
// host-side occupancy gate). Agent-scope atomics only: plain-load spinning
// would read a stale per-XCD L2 line forever (G16). Generation read happens
// before the arrive RMW (release ordering) so no lost-wakeup.
// ---------------------------------------------------------------------------
__device__ __forceinline__ void grid_bar(int* cnt, int* gen) {
    __syncthreads();
    if (threadIdx.x == 0) {
        __threadfence();   // release all prior writes to device scope
        int g = __hip_atomic_load(gen, __ATOMIC_RELAXED, __HIP_MEMORY_SCOPE_AGENT);
        int v = __hip_atomic_fetch_add(cnt, 1, __ATOMIC_ACQ_REL, __HIP_MEMORY_SCOPE_AGENT);
        if (v == NBLK - 1) {
            __hip_atomic_store(cnt, 0, __ATOMIC_RELAXED, __HIP_MEMORY_SCOPE_AGENT);
            __hip_atomic_fetch_add(gen, 1, __ATOMIC_ACQ_REL, __HIP_MEMORY_SCOPE_AGENT);
        } else {
            while (__hip_atomic_load(gen, __ATOMIC_ACQUIRE, __HIP_MEMORY_SCOPE_AGENT) == g)
                __builtin_amdgcn_s_sleep(2);
        }
    }
    __syncthreads();
}

// ---------------------------------------------------------------------------
// Shared GEMM body (R8's verified kernel: 128x128xBK32, XOR swizzle, 0 bank
// conflicts). EPI 0: split0 -> out (+bias), s>0 -> parts[s-1] plain stores.
// EPI 1: atomicAdd into bias-initialized out (fallback).
// ---------------------------------------------------------------------------
template <int EPI, int SK>
__device__ __forceinline__ void gemm_body(
    int nt, int mt, int s, int t,
    const unsigned short* __restrict__ Abf,
    const unsigned short* __restrict__ Wbf,
    const float* __restrict__ bias,
    float* __restrict__ out, float* __restrict__ parts,
    unsigned short* As, unsigned short* Bs) {
    const int w = t >> 6, ln = t & 63;
    const int wm = w & 1, wn = w >> 1;
    const int KSs = K_DIM / SK;
    const int ks0 = s * KSs;

    const int srow = w * 16 + (ln >> 2);
    const int scol = (((ln & 3) ^ ((ln >> 3) & 3)) * 8);
    const unsigned short* gA0 = Abf + (size_t)(mt * BM + srow) * K_DIM + ks0 + scol;
    const unsigned short* gA1 = gA0 + (size_t)64 * K_DIM;
    const unsigned short* gB0 = Wbf + (size_t)(nt * BN + srow) * K_DIM + ks0 + scol;
    const unsigned short* gB1 = gB0 + (size_t)64 * K_DIM;
    unsigned short* lA0 = &As[(w * 16) * BK];
    unsigned short* lA1 = &As[(64 + w * 16) * BK];
    unsigned short* lB0 = &Bs[(w * 16) * BK];
    unsigned short* lB1 = &Bs[(64 + w * 16) * BK];

    const int quad = ln >> 4, lanem = ln & 15;
    const int rsw = (quad ^ ((lanem >> 1) & 3)) * 8;
    const unsigned short* rA = &As[(wm * 64 + lanem) * BK + rsw];
    const unsigned short* rB = &Bs[(wn * 64 + lanem) * BK + rsw];

    f32x4 acc[4][4];
#pragma unroll
    for (int mi = 0; mi < 4; ++mi)
#pragma unroll
        for (int ni = 0; ni < 4; ++ni)
            acc[mi][ni] = (f32x4){0.f, 0.f, 0.f, 0.f};

    for (int kt = 0; kt < KSs / BK; ++kt) {
        __syncthreads();
        gload_lds16(gA0 + kt * BK, lA0);
        gload_lds16(gA1 + kt * BK, lA1);
        gload_lds16(gB0 + kt * BK, lB0);
        gload_lds16(gB1 + kt * BK, lB1);
        __syncthreads();

        bf16x8 af[4], bfr[4];
#pragma unroll
        for (int mi = 0; mi < 4; ++mi) af[mi]  = *(const bf16x8*)(rA + mi * 16 * BK);
#pragma unroll
        for (int ni = 0; ni < 4; ++ni) bfr[ni] = *(const bf16x8*)(rB + ni * 16 * BK);
#pragma unroll
        for (int mi = 0; mi < 4; ++mi)
#pragma unroll
            for (int ni = 0; ni < 4; ++ni)
                acc[mi][ni] = __builtin_amdgcn_mfma_f32_16x16x32_bf16(
                    af[mi], bfr[ni], acc[mi][ni], 0, 0, 0);
    }

    const int row0 = mt * BM + wm * 64 + quad * 4;
    const int col0 = nt * BN + wn * 64 + lanem;
    if (EPI == 0) {
        float bv[4];
#pragma unroll
        for (int ni = 0; ni < 4; ++ni) bv[ni] = (s == 0) ? bias[col0 + ni * 16] : 0.f;
        float* dst = (s == 0) ? out : parts + (size_t)(s - 1) * BATCH * OUT_F;
#pragma unroll
        for (int mi = 0; mi < 4; ++mi)
#pragma unroll
            for (int ni = 0; ni < 4; ++ni)
#pragma unroll
                for (int r = 0; r < 4; ++r)
                    dst[(size_t)(row0 + mi * 16 + r) * OUT_F + col0 + ni * 16] =
                        acc[mi][ni][r] + bv[ni];
    } else {
#pragma unroll
        for (int mi = 0; mi < 4; ++mi)
#pragma unroll
            for (int ni = 0; ni < 4; ++ni)
#pragma unroll
                for (int r = 0; r < 4; ++r)
                    atomicAdd(&out[(size_t)(row0 + mi * 16 + r) * OUT_F + col0 + ni * 16],
                              acc[mi][ni][r]);
    }
}

// ---------------------------------------------------------------------------
// THE fused persistent kernel: A zero-W | B scatter+convert | C gemm | D reduce
// ---------------------------------------------------------------------------
__global__ void __launch_bounds__(256, 4)
fused(const float* __restrict__ x,
      const int* __restrict__ row_idx,
      const int* __restrict__ col_idx,
      const float* __restrict__ values,
      const float* __restrict__ bias,
      float* __restrict__ out,
      int* __restrict__ bar,
      unsigned short* __restrict__ xb,
      unsigned short* __restrict__ W,
      float* __restrict__ parts) {
    __shared__ __align__(16) unsigned short As[BM * BK];
    __shared__ __align__(16) unsigned short Bs[BN * BK];
    const int b = blockIdx.x, t = threadIdx.x;
    const int gtid = b * 256 + t;

    // ---- Phase A: zero W (2,097,152 uint4 over 262,144 threads x 8) ----
    {
        uint4* Wz = (uint4*)W;
#pragma unroll
        for (int j = 0; j < 8; ++j)
            Wz[(size_t)gtid + (size_t)j * (NBLK * 256)] = make_uint4(0, 0, 0, 0);
    }
    grid_bar(bar, bar + 64);

    // ---- Phase B: scatter (blocks 0..819) | convert x (blocks 820..1023).
    // Convert is memory-streaming; scatter is atomic-rate-bound with idle BW,
    // so the convert rides along for free. ----
    if (b < SCAT_BLKS) {
        int i = gtid;                          // entry-quad id
        if (i < NNZ_C / 4) {                   // NNZ_C = 4*209715 exact
            int4   r4 = ((const int4*)row_idx)[i];
            int4   c4 = ((const int4*)col_idx)[i];
            float4 v4 = ((const float4*)values)[i];
            pk_add(W, r4.x, c4.x, v4.x);
            pk_add(W, r4.y, c4.y, v4.y);
            pk_add(W, r4.z, c4.z, v4.z);
            pk_add(W, r4.w, c4.w, v4.w);
        }
    } else {
        for (int j = (b - SCAT_BLKS) * 256 + t; j < N_CVT; j += CVT_BLKS * 256) {
            const float4* p = (const float4*)x + (size_t)j * 2;
            float4 a = p[0], bb = p[1];
            union { unsigned short h[8]; bf16x8 v; } u;
            u.h[0] = f2bf(a.x);  u.h[1] = f2bf(a.y);
            u.h[2] = f2bf(a.z);  u.h[3] = f2bf(a.w);
            u.h[4] = f2bf(bb.x); u.h[5] = f2bf(bb.y);
            u.h[6] = f2bf(bb.z); u.h[7] = f2bf(bb.w);
            ((bf16x8*)xb)[j] = u.v;
        }
    }
    grid_bar(bar, bar + 64);

    // ---- Phase C: gemm, SK=8: b -> (nt = b&31, mt = (b>>5)&3, s = b>>7) ----
    gemm_body<0, 8>(b & 31, (b >> 5) & 3, b >> 7, t, xb, W, bias, out, parts,
                    As, Bs);
    grid_bar(bar, bar + 64);

    // ---- Phase D: out += sum(parts[0..6])  (524,288 float4 / 262,144 thr) ----
#pragma unroll
    for (int j = 0; j < 2; ++j) {
        size_t i = (size_t)gtid + (size_t)j * (NBLK * 256);
        float4 a = ((const float4*)out)[i];
#pragma unroll
        for (int p = 0; p < 7; ++p) {
            float4 v = ((const float4*)(parts + (size_t)p * BATCH * OUT_F))[i];
            a.x += v.x; a.y += v.y; a.z += v.z; a.w += v.w;
        }
        ((float4*)out)[i] = a;
    }
}

// ---------------------------------------------------------------------------
// Fallback multi-kernel path (used only if occupancy/ws gate fails).
// ---------------------------------------------------------------------------
#define N_WZ   (OUT_F * K_DIM / 8)
#define N_OUT  (BATCH * OUT_F / 4)
__global__ void prep(const float* __restrict__ x,
                     unsigned short* __restrict__ xb,
                     const float* __restrict__ bias,
                     float* __restrict__ out,
                     uint4* __restrict__ Wz) {
    int i = blockIdx.x * 256 + threadIdx.x;
    if (i < N_WZ) { Wz[i] = make_uint4(0, 0, 0, 0); return; }
    i -= N_WZ;
    if (i < N_CVT) {
        const float4* p = (const float4*)x + (size_t)i * 2;
        float4 a = p[0], b = p[1];
        union { unsigned short h[8]; bf16x8 v; } u;
        u.h[0] = f2bf(a.x); u.h[1] = f2bf(a.y); u.h[2] = f2bf(a.z); u.h[3] = f2bf(a.w);
        u.h[4] = f2bf(b.x); u.h[5] = f2bf(b.y); u.h[6] = f2bf(b.z); u.h[7] = f2bf(b.w);
        ((bf16x8*)xb)[i] = u.v;
        return;
    }
    i -= N_CVT;
    if (i < N_OUT) {
        float4 b = ((const float4*)bias)[i & (OUT_F / 4 - 1)];
        ((float4*)out)[i] = b;
    }
}
__global__ void scatter_pk(const int* __restrict__ row_idx,
                           const int* __restrict__ col_idx,
                           const float* __restrict__ values,
                           unsigned short* __restrict__ W) {
    int i = blockIdx.x * 256 + threadIdx.x;
    if (i >= NNZ_C / 4) return;
    int4   r4 = ((const int4*)row_idx)[i];
    int4   c4 = ((const int4*)col_idx)[i];
    float4 v4 = ((const float4*)values)[i];
    pk_add(W, r4.x, c4.x, v4.x);
    pk_add(W, r4.y, c4.y, v4.y);
    pk_add(W, r4.z, c4.z, v4.z);
    pk_add(W, r4.w, c4.w, v4.w);
}
__global__ void __launch_bounds__(256)
gemm_atomic(const unsigned short* __restrict__ Abf,
            const unsigned short* __restrict__ Wbf,
            const float* __restrict__ bias,
            float* __restrict__ out) {
    __shared__ __align__(16) unsigned short As[BM * BK];
    __shared__ __align__(16) unsigned short Bs[BN * BK];
    gemm_body<1, 4>(blockIdx.x, blockIdx.y, blockIdx.z, threadIdx.x,
                    Abf, Wbf, bias, out, nullptr, As, Bs);
}

// ---------------------------------------------------------------------------
// ws: bar 256 B | xb 4.19 MB | W 33.55 MB | parts 58.72 MB  -> ~96.5 MB
// ---------------------------------------------------------------------------
extern "C" void kernel_launch(void* const* d_in, const int* in_sizes, int n_in,
                              void* d_out, int out_size, void* d_ws, size_t ws_size,
                              hipStream_t stream) {
    const float* x       = (const float*)d_in[0];
    const int*   row_idx = (const int*)d_in[1];
    const int*   col_idx = (const int*)d_in[2];
    const float* values  = (const float*)d_in[3];
    const float* bias    = (const float*)d_in[4];
    float*       out     = (float*)d_out;

    int* bar = (int*)d_ws;
    unsigned short* xb = (unsigned short*)((char*)d_ws + 256);
    unsigned short* W  = xb + (size_t)BATCH * K_DIM;
    float* parts = (float*)(W + (size_t)OUT_F * K_DIM);
    size_t need = 256 + (size_t)BATCH * K_DIM * 2 + (size_t)OUT_F * K_DIM * 2
                + (size_t)7 * BATCH * OUT_F * 4;

    // Residency gate: fused requires all 1024 blocks co-resident (4/CU).
    int maxb = 0;
    hipError_t e = hipOccupancyMaxActiveBlocksPerMultiprocessor(
        &maxb, (const void*)fused, 256, 0);
    bool coop = (e == hipSuccess) && (maxb >= 4) && (ws_size >= need);

    if (coop) {
        hipMemsetAsync(bar, 0, 256, stream);   // barrier cnt + gen
        fused<<<NBLK, 256, 0, stream>>>(x, row_idx, col_idx, values, bias,
                                        out, bar, xb, W, parts);
    } else {
        prep<<<(N_WZ + N_CVT + N_OUT) / 256, 256, 0, stream>>>(
            x, xb, bias, out, (uint4*)W);
        scatter_pk<<<(NNZ_C / 4 + 255) / 256, 256, 0, stream>>>(
            row_idx, col_idx, values, W);
        gemm_atomic<<<dim3(OUT_F / BN, BATCH / BM, 4), 256, 0, stream>>>(
            xb, W, bias, out);
    }
}

// Round 10
// 168.992 us; speedup vs baseline: 1.0027x; 1.0027x over previous
//
#include <hip/hip_runtime.h>

#define IN_F    4096
#define OUT_F   4096
#define K_DIM   4096
#define NNZ_C   838860
#define NQ      (NNZ_C / 4)              // 209715 entry-quads, exact
#define BATCH   512
#define BK      32
#define BM      128
#define BN      128
#define NBLK    1024                     // 4 blocks/CU x 256 CUs
#define GRPS    8
#define GRP_SZ  (NBLK / GRPS)            // 128
#define N_CVT   (BATCH * K_DIM / 8)      // 262144 = NBLK*256 exactly

typedef short bf16x8 __attribute__((ext_vector_type(8)));
typedef float f32x4  __attribute__((ext_vector_type(4)));

__device__ __forceinline__ unsigned short f2bf(float f) {  // RNE fp32->bf16
    unsigned u = __float_as_uint(f);
    u += 0x7fffu + ((u >> 16) & 1u);
    return (unsigned short)(u >> 16);
}
__device__ __forceinline__ void gload_lds16(const void* g, void* l) {
    __builtin_amdgcn_global_load_lds(
        (const __attribute__((address_space(1))) unsigned int*)g,
        (__attribute__((address_space(3))) unsigned int*)l, 16, 0, 0);
}
__device__ __forceinline__ void pk_add(unsigned short* W, unsigned idx, float v) {
    unsigned short h = f2bf(v);
    unsigned data = (idx & 1u) ? ((unsigned)h << 16) : (unsigned)h;
    unsigned long long addr = (unsigned long long)(W + (idx & ~1u));
    asm volatile("global_atomic_pk_add_bf16 %0, %1, off"
                 :: "v"(addr), "v"(data) : "memory");
}

// ---------------------------------------------------------------------------
// Grid barrier v2 -- SHARDED (R9 post-mortem: single-line barrier ~15-20 us
// because 1024 spinners hammer one line cross-XCD). 8 arrival counters
// (128 blocks each), 8 spin lines, one 8-way final stage. Layout in ints,
// stride 32 (128 B): cnt[g]=bs[g*32], gcnt=bs[256], lgen[g]=bs[320+g*32].
// fence-release before arrive; acquire spin (wb/inv validated by R9 pass).
// ---------------------------------------------------------------------------
__device__ __forceinline__ void grid_bar(int* bs) {
    __syncthreads();
    if (threadIdx.x == 0) {
        const int grp = blockIdx.x & (GRPS - 1);
        int* cnt  = bs + grp * 32;
        int* gcnt = bs + 256;
        int* lgen = bs + 320 + grp * 32;
        __threadfence();
        int g = __hip_atomic_load(lgen, __ATOMIC_RELAXED, __HIP_MEMORY_SCOPE_AGENT);
        int v = __hip_atomic_fetch_add(cnt, 1, __ATOMIC_ACQ_REL, __HIP_MEMORY_SCOPE_AGENT);
        if (v == GRP_SZ - 1) {
            int w = __hip_atomic_fetch_add(gcnt, 1, __ATOMIC_ACQ_REL, __HIP_MEMORY_SCOPE_AGENT);
            if (w == GRPS - 1) {
                __hip_atomic_store(gcnt, 0, __ATOMIC_RELAXED, __HIP_MEMORY_SCOPE_AGENT);
#pragma unroll
                for (int j = 0; j < GRPS; ++j)
                    __hip_atomic_store(bs + j * 32, 0, __ATOMIC_RELAXED, __HIP_MEMORY_SCOPE_AGENT);
#pragma unroll
                for (int j = 0; j < GRPS; ++j)
                    __hip_atomic_fetch_add(bs + 320 + j * 32, 1,
                                           __ATOMIC_RELEASE, __HIP_MEMORY_SCOPE_AGENT);
            } else {
                while (__hip_atomic_load(lgen, __ATOMIC_ACQUIRE, __HIP_MEMORY_SCOPE_AGENT) == g)
                    __builtin_amdgcn_s_sleep(2);
            }
        } else {
            while (__hip_atomic_load(lgen, __ATOMIC_ACQUIRE, __HIP_MEMORY_SCOPE_AGENT) == g)
                __builtin_amdgcn_s_sleep(4);
        }
    }
    __syncthreads();
}

// ---------------------------------------------------------------------------
// R8's verified GEMM body: 128x128xBK32, XOR swizzle (0 bank conflicts).
// EPI 0: split0 -> out (+bias), s>0 -> parts[s-1], plain stores.
// EPI 1: atomicAdd into bias-initialized out (fallback).
// ---------------------------------------------------------------------------
template <int EPI, int SK>
__device__ __forceinline__ void gemm_body(
    int nt, int mt, int s, int t,
    const unsigned short* __restrict__ Abf,
    const unsigned short* __restrict__ Wbf,
    const float* __restrict__ bias,
    float* __restrict__ out, float* __restrict__ parts,
    unsigned short* As, unsigned short* Bs) {
    const int w = t >> 6, ln = t & 63;
    const int wm = w & 1, wn = w >> 1;
    const int KSs = K_DIM / SK;
    const int ks0 = s * KSs;

    const int srow = w * 16 + (ln >> 2);
    const int scol = (((ln & 3) ^ ((ln >> 3) & 3)) * 8);
    const unsigned short* gA0 = Abf + (size_t)(mt * BM + srow) * K_DIM + ks0 + scol;
    const unsigned short* gA1 = gA0 + (size_t)64 * K_DIM;
    const unsigned short* gB0 = Wbf + (size_t)(nt * BN + srow) * K_DIM + ks0 + scol;
    const unsigned short* gB1 = gB0 + (size_t)64 * K_DIM;
    unsigned short* lA0 = &As[(w * 16) * BK];
    unsigned short* lA1 = &As[(64 + w * 16) * BK];
    unsigned short* lB0 = &Bs[(w * 16) * BK];
    unsigned short* lB1 = &Bs[(64 + w * 16) * BK];

    const int quad = ln >> 4, lanem = ln & 15;
    const int rsw = (quad ^ ((lanem >> 1) & 3)) * 8;
    const unsigned short* rA = &As[(wm * 64 + lanem) * BK + rsw];
    const unsigned short* rB = &Bs[(wn * 64 + lanem) * BK + rsw];

    f32x4 acc[4][4];
#pragma unroll
    for (int mi = 0; mi < 4; ++mi)
#pragma unroll
        for (int ni = 0; ni < 4; ++ni)
            acc[mi][ni] = (f32x4){0.f, 0.f, 0.f, 0.f};

    for (int kt = 0; kt < KSs / BK; ++kt) {
        __syncthreads();
        gload_lds16(gA0 + kt * BK, lA0);
        gload_lds16(gA1 + kt * BK, lA1);
        gload_lds16(gB0 + kt * BK, lB0);
        gload_lds16(gB1 + kt * BK, lB1);
        __syncthreads();

        bf16x8 af[4], bfr[4];
#pragma unroll
        for (int mi = 0; mi < 4; ++mi) af[mi]  = *(const bf16x8*)(rA + mi * 16 * BK);
#pragma unroll
        for (int ni = 0; ni < 4; ++ni) bfr[ni] = *(const bf16x8*)(rB + ni * 16 * BK);
#pragma unroll
        for (int mi = 0; mi < 4; ++mi)
#pragma unroll
            for (int ni = 0; ni < 4; ++ni)
                acc[mi][ni] = __builtin_amdgcn_mfma_f32_16x16x32_bf16(
                    af[mi], bfr[ni], acc[mi][ni], 0, 0, 0);
    }

    const int row0 = mt * BM + wm * 64 + quad * 4;
    const int col0 = nt * BN + wn * 64 + lanem;
    if (EPI == 0) {
        float bv[4];
#pragma unroll
        for (int ni = 0; ni < 4; ++ni) bv[ni] = (s == 0) ? bias[col0 + ni * 16] : 0.f;
        float* dst = (s == 0) ? out : parts + (size_t)(s - 1) * BATCH * OUT_F;
#pragma unroll
        for (int mi = 0; mi < 4; ++mi)
#pragma unroll
            for (int ni = 0; ni < 4; ++ni)
#pragma unroll
                for (int r = 0; r < 4; ++r)
                    dst[(size_t)(row0 + mi * 16 + r) * OUT_F + col0 + ni * 16] =
                        acc[mi][ni][r] + bv[ni];
    } else {
#pragma unroll
        for (int mi = 0; mi < 4; ++mi)
#pragma unroll
            for (int ni = 0; ni < 4; ++ni)
#pragma unroll
                for (int r = 0; r < 4; ++r)
                    atomicAdd(&out[(size_t)(row0 + mi * 16 + r) * OUT_F + col0 + ni * 16],
                              acc[mi][ni][r]);
    }
}

// ---------------------------------------------------------------------------
// Fused persistent kernel.
//  A: zero W | convert x | tag-store T[idx]=entry_id   (all independent)
//  B: gather T (device-scope loads); winner (T[idx]==id) plain-stores bf16(v)
//     into W; loser mask kept IN REGISTERS across the barrier
//  C: losers (~21K birthday dups) pk_add  -- the only scatter atomics left
//  D: R8 gemm, SK=8, parts epilogue
//  E: out += sum(parts)
// Tag dedup exactness: ids unique -> exactly one winner per touched slot;
// losers add after the barrier => same bf16 sum semantics as R8 (absmax~0.25).
// Plain partial-line cross-XCD stores validated by R4; fence/acquire
// visibility validated by R9.
// ---------------------------------------------------------------------------
__global__ void __launch_bounds__(256, 4)
fused(const float* __restrict__ x,
      const int* __restrict__ row_idx,
      const int* __restrict__ col_idx,
      const float* __restrict__ values,
      const float* __restrict__ bias,
      float* __restrict__ out,
      int* __restrict__ bs,
      unsigned short* __restrict__ xb,
      unsigned short* __restrict__ W,
      int* __restrict__ T,
      float* __restrict__ parts) {
    __shared__ __align__(16) unsigned short As[BM * BK];
    __shared__ __align__(16) unsigned short Bs[BN * BK];
    const int b = blockIdx.x, t = threadIdx.x;
    const int gtid = b * 256 + t;

    // ---- Phase A ----
    {
        uint4* Wz = (uint4*)W;
#pragma unroll
        for (int j = 0; j < 8; ++j)
            Wz[(size_t)gtid + (size_t)j * (NBLK * 256)] = make_uint4(0, 0, 0, 0);
        // convert: exactly one bf16x8 per thread
        const float4* p = (const float4*)x + (size_t)gtid * 2;
        float4 a = p[0], bb = p[1];
        union { unsigned short h[8]; bf16x8 v; } u;
        u.h[0] = f2bf(a.x);  u.h[1] = f2bf(a.y);
        u.h[2] = f2bf(a.z);  u.h[3] = f2bf(a.w);
        u.h[4] = f2bf(bb.x); u.h[5] = f2bf(bb.y);
        u.h[6] = f2bf(bb.z); u.h[7] = f2bf(bb.w);
        ((bf16x8*)xb)[gtid] = u.v;
    }
    unsigned eidx[4];
    float    ev[4];
    bool     have = (gtid < NQ);
    if (have) {
        int4   r4 = ((const int4*)row_idx)[gtid];
        int4   c4 = ((const int4*)col_idx)[gtid];
        float4 v4 = ((const float4*)values)[gtid];
        eidx[0] = (unsigned)r4.x * K_DIM + (unsigned)c4.x;  ev[0] = v4.x;
        eidx[1] = (unsigned)r4.y * K_DIM + (unsigned)c4.y;  ev[1] = v4.y;
        eidx[2] = (unsigned)r4.z * K_DIM + (unsigned)c4.z;  ev[2] = v4.z;
        eidx[3] = (unsigned)r4.w * K_DIM + (unsigned)c4.w;  ev[3] = v4.w;
#pragma unroll
        for (int j = 0; j < 4; ++j)
            T[eidx[j]] = 4 * gtid + j;       // plain store, last-writer-wins
    }
    grid_bar(bs);

    // ---- Phase B: winners store; remember losers ----
    int lose_mask = 0;
    if (have) {
#pragma unroll
        for (int j = 0; j < 4; ++j) {
            // device-scope load: always reads the coherent point (no stale L2)
            int tag = __hip_atomic_load(&T[eidx[j]], __ATOMIC_RELAXED,
                                        __HIP_MEMORY_SCOPE_AGENT);
            if (tag == 4 * gtid + j)
                W[eidx[j]] = f2bf(ev[j]);    // plain 2B store
            else
                lose_mask |= (1 << j);
        }
    }
    grid_bar(bs);

    // ---- Phase C: duplicate losers add atomically (~21K total) ----
    if (lose_mask) {
#pragma unroll
        for (int j = 0; j < 4; ++j)
            if (lose_mask & (1 << j)) pk_add(W, eidx[j], ev[j]);
    }
    grid_bar(bs);

    // ---- Phase D: gemm, SK=8: b -> (nt=b&31, mt=(b>>5)&3, s=b>>7) ----
    gemm_body<0, 8>(b & 31, (b >> 5) & 3, b >> 7, t, xb, W, bias, out, parts,
                    As, Bs);
    grid_bar(bs);

    // ---- Phase E: out += sum(parts[0..6]) ----
#pragma unroll
    for (int j = 0; j < 2; ++j) {
        size_t i = (size_t)gtid + (size_t)j * (NBLK * 256);
        float4 a = ((const float4*)out)[i];
#pragma unroll
        for (int p = 0; p < 7; ++p) {
            float4 v = ((const float4*)(parts + (size_t)p * BATCH * OUT_F))[i];
            a.x += v.x; a.y += v.y; a.z += v.z; a.w += v.w;
        }
        ((float4*)out)[i] = a;
    }
}

// ---------------------------------------------------------------------------
// Fallback multi-kernel path (R8/R9-proven) if gates fail.
// ---------------------------------------------------------------------------
#define N_WZ   (OUT_F * K_DIM / 8)
#define N_OUT  (BATCH * OUT_F / 4)
__global__ void prep(const float* __restrict__ x,
                     unsigned short* __restrict__ xb,
                     const float* __restrict__ bias,
                     float* __restrict__ out,
                     uint4* __restrict__ Wz) {
    int i = blockIdx.x * 256 + threadIdx.x;
    if (i < N_WZ) { Wz[i] = make_uint4(0, 0, 0, 0); return; }
    i -= N_WZ;
    if (i < N_CVT) {
        const float4* p = (const float4*)x + (size_t)i * 2;
        float4 a = p[0], b = p[1];
        union { unsigned short h[8]; bf16x8 v; } u;
        u.h[0] = f2bf(a.x); u.h[1] = f2bf(a.y); u.h[2] = f2bf(a.z); u.h[3] = f2bf(a.w);
        u.h[4] = f2bf(b.x); u.h[5] = f2bf(b.y); u.h[6] = f2bf(b.z); u.h[7] = f2bf(b.w);
        ((bf16x8*)xb)[i] = u.v;
        return;
    }
    i -= N_CVT;
    if (i < N_OUT) {
        float4 b = ((const float4*)bias)[i & (OUT_F / 4 - 1)];
        ((float4*)out)[i] = b;
    }
}
__global__ void scatter_pk(const int* __restrict__ row_idx,
                           const int* __restrict__ col_idx,
                           const float* __restrict__ values,
                           unsigned short* __restrict__ W) {
    int i = blockIdx.x * 256 + threadIdx.x;
    if (i >= NQ) return;
    int4   r4 = ((const int4*)row_idx)[i];
    int4   c4 = ((const int4*)col_idx)[i];
    float4 v4 = ((const float4*)values)[i];
    pk_add(W, (unsigned)r4.x * K_DIM + (unsigned)c4.x, v4.x);
    pk_add(W, (unsigned)r4.y * K_DIM + (unsigned)c4.y, v4.y);
    pk_add(W, (unsigned)r4.z * K_DIM + (unsigned)c4.z, v4.z);
    pk_add(W, (unsigned)r4.w * K_DIM + (unsigned)c4.w, v4.w);
}
__global__ void __launch_bounds__(256)
gemm_atomic(const unsigned short* __restrict__ Abf,
            const unsigned short* __restrict__ Wbf,
            const float* __restrict__ bias,
            float* __restrict__ out) {
    __shared__ __align__(16) unsigned short As[BM * BK];
    __shared__ __align__(16) unsigned short Bs[BN * BK];
    gemm_body<1, 4>(blockIdx.x, blockIdx.y, blockIdx.z, threadIdx.x,
                    Abf, Wbf, bias, out, nullptr, As, Bs);
}

// ---------------------------------------------------------------------------
// ws: bar 4 KB | xb 4.19 MB | W 33.55 MB | T 67.11 MB | parts 58.72 MB
//     total ~163.6 MB (ws observed ~268 MB in R9 profile poison-fill).
// ---------------------------------------------------------------------------
extern "C" void kernel_launch(void* const* d_in, const int* in_sizes, int n_in,
                              void* d_out, int out_size, void* d_ws, size_t ws_size,
                              hipStream_t stream) {
    const float* x       = (const float*)d_in[0];
    const int*   row_idx = (const int*)d_in[1];
    const int*   col_idx = (const int*)d_in[2];
    const float* values  = (const float*)d_in[3];
    const float* bias    = (const float*)d_in[4];
    float*       out     = (float*)d_out;

    char* p = (char*)d_ws;
    int* bs = (int*)p;                       p += 4096;
    unsigned short* xb = (unsigned short*)p; p += (size_t)BATCH * K_DIM * 2;
    unsigned short* W  = (unsigned short*)p; p += (size_t)OUT_F * K_DIM * 2;
    int* T = (int*)p;                        p += (size_t)OUT_F * K_DIM * 4;
    float* parts = (float*)p;                p += (size_t)7 * BATCH * OUT_F * 4;
    size_t need_full = (size_t)(p - (char*)d_ws);

    int maxb = 0;
    hipError_t e = hipOccupancyMaxActiveBlocksPerMultiprocessor(
        &maxb, (const void*)fused, 256, 0);
    bool coop = (e == hipSuccess) && (maxb >= 4) && (ws_size >= need_full);

    if (coop) {
        hipMemsetAsync(bs, 0, 4096, stream);
        fused<<<NBLK, 256, 0, stream>>>(x, row_idx, col_idx, values, bias,
                                        out, bs, xb, W, T, parts);
    } else {
        prep<<<(N_WZ + N_CVT + N_OUT) / 256, 256, 0, stream>>>(
            x, xb, bias, out, (uint4*)W);
        scatter_pk<<<(NQ + 255) / 256, 256, 0, stream>>>(
            row_idx, col_idx, values, W);
        gemm_atomic<<<dim3(OUT_F / BN, BATCH / BM, 4), 256, 0, stream>>>(
            xb, W, bias, out);
    }
}